// Round 2
// baseline (31468.512 us; speedup 1.0000x reference)
//
#include <hip/hip_runtime.h>
#include <cstdint>
#include <cstddef>

#define D 256
#define H 8
#define DFF 1024

static inline int cdiv(int a, int b) { return (a + b - 1) / b; }

// ---------------------------------------------------------------------------
// zero-fill (float4 vectorized); count = number of floats, multiple of 4
// ---------------------------------------------------------------------------
__global__ __launch_bounds__(256) void zero_kernel(float* __restrict__ p, int count4)
{
    int i = blockIdx.x * blockDim.x + threadIdx.x;
    if (i < count4) ((float4*)p)[i] = make_float4(0.f, 0.f, 0.f, 0.f);
}

// ---------------------------------------------------------------------------
// Generic tiled fp32 GEMM: C[M,Nc] = A[M,K] @ B[K,Nc] (+bias) (+resid) (relu?)
// 64x64 tile, 256 threads, 4x4 microtile/thread, K-step 16.
// In-place safe when resid==C (each thread reads resid[i] then writes C[i]).
// ---------------------------------------------------------------------------
__global__ __launch_bounds__(256) void gemm_kernel(
    const float* __restrict__ A, int M, int K,
    const float* __restrict__ B, int Ncols,
    const float* __restrict__ bias,
    const float* __restrict__ resid,
    float* __restrict__ C, int relu)
{
    __shared__ float As[16][68];  // [k][m], padded
    __shared__ float Bs[16][68];  // [k][n]

    const int tid = threadIdx.x;
    const int row0 = blockIdx.x * 64;
    const int col0 = blockIdx.y * 64;
    const int tx = tid & 15;      // 0..15 -> 4 cols each
    const int ty = tid >> 4;      // 0..15 -> 4 rows each

    const int arow = tid >> 2;           // 0..63
    const int ak   = (tid & 3) * 4;      // 0,4,8,12
    const int bk   = tid >> 4;           // 0..15
    const int bcol = (tid & 15) * 4;     // 0..60

    float acc[4][4] = {};

    for (int k0 = 0; k0 < K; k0 += 16) {
        float4 a4 = make_float4(0.f, 0.f, 0.f, 0.f);
        int gr = row0 + arow;
        if (gr < M) a4 = *(const float4*)&A[(size_t)gr * K + k0 + ak];
        As[ak + 0][arow] = a4.x;
        As[ak + 1][arow] = a4.y;
        As[ak + 2][arow] = a4.z;
        As[ak + 3][arow] = a4.w;

        float4 b4 = *(const float4*)&B[(size_t)(k0 + bk) * Ncols + col0 + bcol];
        *(float4*)&Bs[bk][bcol] = b4;

        __syncthreads();

        #pragma unroll
        for (int kk = 0; kk < 16; ++kk) {
            float4 av4 = *(const float4*)&As[kk][ty * 4];
            float4 bv4 = *(const float4*)&Bs[kk][tx * 4];
            float a_[4] = {av4.x, av4.y, av4.z, av4.w};
            float b_[4] = {bv4.x, bv4.y, bv4.z, bv4.w};
            #pragma unroll
            for (int i = 0; i < 4; ++i)
                #pragma unroll
                for (int j = 0; j < 4; ++j)
                    acc[i][j] = fmaf(a_[i], b_[j], acc[i][j]);
        }
        __syncthreads();
    }

    #pragma unroll
    for (int i = 0; i < 4; ++i) {
        int gr = row0 + ty * 4 + i;
        if (gr >= M) continue;
        #pragma unroll
        for (int j = 0; j < 4; ++j) {
            int gc = col0 + tx * 4 + j;
            float val = acc[i][j];
            if (bias)  val += bias[gc];
            if (resid) val += resid[(size_t)gr * Ncols + gc];
            if (relu)  val = fmaxf(val, 0.f);
            C[(size_t)gr * Ncols + gc] = val;
        }
    }
}

// ---------------------------------------------------------------------------
// Edge attention: one wave (64 lanes) per edge.
// lane i covers feature elems [4i,4i+4) -> head = i/8.
// ---------------------------------------------------------------------------
__global__ __launch_bounds__(256) void edge_attn_kernel(
    const float* __restrict__ q, const float* __restrict__ k,
    const float* __restrict__ v,
    const int* __restrict__ esrc, const int* __restrict__ edst,
    float* __restrict__ wv, float* __restrict__ z, int E)
{
    int e = (blockIdx.x * blockDim.x + threadIdx.x) >> 6;
    int lane = threadIdx.x & 63;
    if (e >= E) return;
    int s = esrc[e], d = edst[e];

    const float4 k4 = *(const float4*)&k[(size_t)s * D + lane * 4];
    const float4 q4 = *(const float4*)&q[(size_t)d * D + lane * 4];
    float p = k4.x * q4.x + k4.y * q4.y + k4.z * q4.z + k4.w * q4.w;
    p += __shfl_xor(p, 1);
    p += __shfl_xor(p, 2);
    p += __shfl_xor(p, 4);

    const float inv_sqrt_dk = 0.17677669529663687f;  // 1/sqrt(32)
    float sc = __expf(fminf(fmaxf(p * inv_sqrt_dk, -5.f), 5.f));

    const float4 v4 = *(const float4*)&v[(size_t)s * D + lane * 4];
    float* wvd = &wv[(size_t)d * D + lane * 4];
    atomicAdd(wvd + 0, v4.x * sc);
    atomicAdd(wvd + 1, v4.y * sc);
    atomicAdd(wvd + 2, v4.z * sc);
    atomicAdd(wvd + 3, v4.w * sc);
    if ((lane & 7) == 0) atomicAdd(&z[(size_t)d * H + (lane >> 3)], sc);
}

// wv[n,h,dk] /= z[n,h]
__global__ __launch_bounds__(256) void div_z_kernel(
    float* __restrict__ wv, const float* __restrict__ z, int total)
{
    int i = blockIdx.x * blockDim.x + threadIdx.x;
    if (i >= total) return;
    int n = i >> 8;
    int h = (i & 255) >> 5;
    wv[i] = wv[i] / z[(size_t)n * H + h];
}

// in-place LayerNorm over rows of length 256; one 256-thread block per row
__global__ __launch_bounds__(256) void layernorm_kernel(
    float* __restrict__ x, const float* __restrict__ g,
    const float* __restrict__ b, int M)
{
    int row = blockIdx.x;
    if (row >= M) return;
    int t = threadIdx.x;
    float val = x[(size_t)row * D + t];
    float s = val, s2 = val * val;
    #pragma unroll
    for (int o = 1; o < 64; o <<= 1) {
        s  += __shfl_xor(s, o);
        s2 += __shfl_xor(s2, o);
    }
    __shared__ float red[8];
    int wave = t >> 6;
    if ((t & 63) == 0) { red[wave] = s; red[4 + wave] = s2; }
    __syncthreads();
    s  = red[0] + red[1] + red[2] + red[3];
    s2 = red[4] + red[5] + red[6] + red[7];
    float mean = s * (1.f / 256.f);
    float var  = s2 * (1.f / 256.f) - mean * mean;
    float r = rsqrtf(var + 1e-5f);
    x[(size_t)row * D + t] = (val - mean) * r * g[t] + b[t];
}

// ---------------------------------------------------------------------------
extern "C" void kernel_launch(void* const* d_in, const int* in_sizes, int n_in,
                              void* d_out, int out_size, void* d_ws, size_t ws_size,
                              hipStream_t stream)
{
    const float* x0   = (const float*)d_in[0];
    const int* esrc   = (const int*)d_in[1];
    const int* edst   = (const int*)d_in[2];
    const float* Wq   = (const float*)d_in[3];
    const float* bq   = (const float*)d_in[4];
    const float* Wk   = (const float*)d_in[5];
    const float* Wv   = (const float*)d_in[6];
    const float* Wo   = (const float*)d_in[7];
    const float* bo   = (const float*)d_in[8];
    const float* ln1g = (const float*)d_in[9];
    const float* ln1b = (const float*)d_in[10];
    const float* W1   = (const float*)d_in[11];
    const float* b1   = (const float*)d_in[12];
    const float* W2   = (const float*)d_in[13];
    const float* b2   = (const float*)d_in[14];
    const float* ln2g = (const float*)d_in[15];
    const float* ln2b = (const float*)d_in[16];

    const int N = in_sizes[0] / D;
    const int E = in_sizes[1];
    const int L = in_sizes[3] / (D * D);
    const size_t ND = (size_t)N * D;

    // workspace layout (floats): bufX | q | k | v | wv | z
    //   t1 (N x DFF = 4*ND) aliases [q..wv] during the FFN (q,k,v,wv dead there)
    // total = 5*ND + N*H floats ~= 258 MB
    float* bufX = (float*)d_ws;
    float* q    = bufX + ND;
    float* k    = q + ND;
    float* v    = k + ND;
    float* wv   = v + ND;
    float* z    = wv + ND;
    float* t1   = q;  // alias: N x DFF spans q,k,v,wv exactly

    dim3 blk(256);
    dim3 gQKV(cdiv(N, 64), D / 64);      // 782 x 4
    dim3 gFF1(cdiv(N, 64), DFF / 64);    // 782 x 16
    int edgeBlocks = cdiv(E, 4);         // 4 waves/block, 1 wave/edge
    int divBlocks  = cdiv((int)ND, 256);
    int zeroCount4 = (int)((ND + (size_t)N * H) / 4);  // wv and z are adjacent
    int zeroBlocks = cdiv(zeroCount4, 256);

    const float* xin = x0;
    for (int l = 0; l < L; ++l) {
        // layers 0..L-2 accumulate in bufX (in-place safe); last layer -> d_out
        float* xout = (l == L - 1) ? (float*)d_out : bufX;
        const float* Wq_l = Wq + (size_t)l * D * D;
        const float* Wk_l = Wk + (size_t)l * D * D;
        const float* Wv_l = Wv + (size_t)l * D * D;
        const float* Wo_l = Wo + (size_t)l * D * D;
        const float* W1_l = W1 + (size_t)l * D * DFF;
        const float* W2_l = W2 + (size_t)l * DFF * D;

        // q = x@Wq + bq ; k = x@Wk ; v = x@Wv
        gemm_kernel<<<gQKV, blk, 0, stream>>>(xin, N, D, Wq_l, D, bq + l * D, nullptr, q, 0);
        gemm_kernel<<<gQKV, blk, 0, stream>>>(xin, N, D, Wk_l, D, nullptr, nullptr, k, 0);
        gemm_kernel<<<gQKV, blk, 0, stream>>>(xin, N, D, Wv_l, D, nullptr, nullptr, v, 0);

        // zero wv and z (adjacent), then edge attention
        zero_kernel<<<zeroBlocks, blk, 0, stream>>>(wv, zeroCount4);
        edge_attn_kernel<<<edgeBlocks, blk, 0, stream>>>(q, k, v, esrc, edst, wv, z, E);
        div_z_kernel<<<divBlocks, blk, 0, stream>>>(wv, z, (int)ND);

        // h = LN(x + wv@Wo + bo) -> xout (resid may equal C only via same-elem path)
        gemm_kernel<<<gQKV, blk, 0, stream>>>(wv, N, D, Wo_l, D, bo + l * D, xin, xout, 0);
        layernorm_kernel<<<N, blk, 0, stream>>>(xout, ln1g + l * D, ln1b + l * D, N);

        // ffn: t1 = relu(xout@W1 + b1); xout = LN(xout + t1@W2 + b2)
        gemm_kernel<<<gFF1, blk, 0, stream>>>(xout, N, D, W1_l, DFF, b1 + l * DFF, nullptr, t1, 1);
        gemm_kernel<<<gQKV, blk, 0, stream>>>(t1, N, DFF, W2_l, D, b2 + l * D, xout, xout, 0);
        layernorm_kernel<<<N, blk, 0, stream>>>(xout, ln2g + l * D, ln2b + l * D, N);

        xin = xout;
    }
}

// Round 3
// 11078.182 us; speedup vs baseline: 2.8406x; 2.8406x over previous
//
#include <hip/hip_runtime.h>
#include <cstdint>
#include <cstddef>

#define D 256
#define H 8
#define DFF 1024

static inline int cdiv(int a, int b) { return (a + b - 1) / b; }

// ---------------------------------------------------------------------------
// int zero-fill
// ---------------------------------------------------------------------------
__global__ __launch_bounds__(256) void zero_int_kernel(int* __restrict__ p, int count)
{
    int i = blockIdx.x * blockDim.x + threadIdx.x;
    if (i < count) p[i] = 0;
}

// deg[dst]++ per edge
__global__ __launch_bounds__(256) void count_deg_kernel(
    const int* __restrict__ edst, int* __restrict__ deg, int E)
{
    int e = blockIdx.x * blockDim.x + threadIdx.x;
    if (e < E) atomicAdd(&deg[edst[e]], 1);
}

// per-block (256 elems) sums of deg
__global__ __launch_bounds__(256) void block_sum_kernel(
    const int* __restrict__ deg, int* __restrict__ bsum, int N)
{
    int t = threadIdx.x;
    int gid = blockIdx.x * 256 + t;
    int val = (gid < N) ? deg[gid] : 0;
    #pragma unroll
    for (int o = 1; o < 64; o <<= 1) val += __shfl_xor(val, o);
    __shared__ int r[4];
    if ((t & 63) == 0) r[t >> 6] = val;
    __syncthreads();
    if (t == 0) bsum[blockIdx.x] = r[0] + r[1] + r[2] + r[3];
}

// single-block exclusive scan of bsum[nb], nb <= 256
__global__ __launch_bounds__(256) void scan_bsum_kernel(int* __restrict__ bsum, int nb)
{
    __shared__ int tmp[256];
    int t = threadIdx.x;
    int val = (t < nb) ? bsum[t] : 0;
    tmp[t] = val;
    __syncthreads();
    for (int off = 1; off < 256; off <<= 1) {
        int add = (t >= off) ? tmp[t - off] : 0;
        __syncthreads();
        tmp[t] += add;
        __syncthreads();
    }
    if (t < nb) bsum[t] = tmp[t] - val;  // exclusive
}

// block-local exclusive scan + block offset -> rowptr, cursor.
// SAFE if cursor aliases deg (each thread reads deg[gid] before writing).
__global__ __launch_bounds__(256) void scan_write_kernel(
    const int* __restrict__ deg, const int* __restrict__ bsum,
    int* __restrict__ rowptr, int* __restrict__ cursor, int N)
{
    __shared__ int tmp[256];
    int t = threadIdx.x;
    int gid = blockIdx.x * 256 + t;
    int val = (gid < N) ? deg[gid] : 0;
    tmp[t] = val;
    __syncthreads();
    for (int off = 1; off < 256; off <<= 1) {
        int add = (t >= off) ? tmp[t - off] : 0;
        __syncthreads();
        tmp[t] += add;
        __syncthreads();
    }
    int excl = tmp[t] - val + bsum[blockIdx.x];
    if (gid < N) { rowptr[gid] = excl; cursor[gid] = excl; }
    if (gid == N - 1) rowptr[N] = excl + val;
}

// scatter src ids into CSR slots
__global__ __launch_bounds__(256) void fill_csr_kernel(
    const int* __restrict__ esrc, const int* __restrict__ edst,
    int* __restrict__ cursor, int* __restrict__ csr_src, int E)
{
    int e = blockIdx.x * blockDim.x + threadIdx.x;
    if (e < E) {
        int pos = atomicAdd(&cursor[edst[e]], 1);
        csr_src[pos] = esrc[e];
    }
}

// ---------------------------------------------------------------------------
// Generic tiled fp32 GEMM: C[M,Nc] = A[M,K] @ B[K,Nc] (+bias) (+resid) (relu?)
// 64x64 tile, 256 threads, 4x4 microtile/thread, K-step 16.
// In-place safe when resid==C.
// ---------------------------------------------------------------------------
__global__ __launch_bounds__(256) void gemm_kernel(
    const float* __restrict__ A, int M, int K,
    const float* __restrict__ B, int Ncols,
    const float* __restrict__ bias,
    const float* __restrict__ resid,
    float* __restrict__ C, int relu)
{
    __shared__ float As[16][68];
    __shared__ float Bs[16][68];

    const int tid = threadIdx.x;
    const int row0 = blockIdx.x * 64;
    const int col0 = blockIdx.y * 64;
    const int tx = tid & 15;
    const int ty = tid >> 4;

    const int arow = tid >> 2;
    const int ak   = (tid & 3) * 4;
    const int bk   = tid >> 4;
    const int bcol = (tid & 15) * 4;

    float acc[4][4] = {};

    for (int k0 = 0; k0 < K; k0 += 16) {
        float4 a4 = make_float4(0.f, 0.f, 0.f, 0.f);
        int gr = row0 + arow;
        if (gr < M) a4 = *(const float4*)&A[(size_t)gr * K + k0 + ak];
        As[ak + 0][arow] = a4.x;
        As[ak + 1][arow] = a4.y;
        As[ak + 2][arow] = a4.z;
        As[ak + 3][arow] = a4.w;

        float4 b4 = *(const float4*)&B[(size_t)(k0 + bk) * Ncols + col0 + bcol];
        *(float4*)&Bs[bk][bcol] = b4;

        __syncthreads();

        #pragma unroll
        for (int kk = 0; kk < 16; ++kk) {
            float4 av4 = *(const float4*)&As[kk][ty * 4];
            float4 bv4 = *(const float4*)&Bs[kk][tx * 4];
            float a_[4] = {av4.x, av4.y, av4.z, av4.w};
            float b_[4] = {bv4.x, bv4.y, bv4.z, bv4.w};
            #pragma unroll
            for (int i = 0; i < 4; ++i)
                #pragma unroll
                for (int j = 0; j < 4; ++j)
                    acc[i][j] = fmaf(a_[i], b_[j], acc[i][j]);
        }
        __syncthreads();
    }

    #pragma unroll
    for (int i = 0; i < 4; ++i) {
        int gr = row0 + ty * 4 + i;
        if (gr >= M) continue;
        #pragma unroll
        for (int j = 0; j < 4; ++j) {
            int gc = col0 + tx * 4 + j;
            float val = acc[i][j];
            if (bias)  val += bias[gc];
            if (resid) val += resid[(size_t)gr * Ncols + gc];
            if (relu)  val = fmaxf(val, 0.f);
            C[(size_t)gr * Ncols + gc] = val;
        }
    }
}

// ---------------------------------------------------------------------------
// Fused per-node attention aggregate: one wave per dst node.
// lane i covers feature elems [4i,4i+4) -> head = i/8.
// Reads q[node] once; loops CSR in-edges; accumulates v[src]*score and z in
// registers; writes o[node] = acc/z. No atomics. SAFE if o aliases q
// (q[node] only ever read by node's own wave, before the write).
// ---------------------------------------------------------------------------
__global__ __launch_bounds__(256) void node_attn_kernel(
    const float* __restrict__ q, const float* __restrict__ k,
    const float* __restrict__ v,
    const int* __restrict__ rowptr, const int* __restrict__ csr_src,
    float* __restrict__ o, int N)
{
    int node = (blockIdx.x * blockDim.x + threadIdx.x) >> 6;
    int lane = threadIdx.x & 63;
    if (node >= N) return;

    const float4 q4 = *(const float4*)&q[(size_t)node * D + lane * 4];
    float4 acc = make_float4(0.f, 0.f, 0.f, 0.f);
    float zacc = 0.f;

    const float inv_sqrt_dk = 0.17677669529663687f;  // 1/sqrt(32)
    int beg = rowptr[node], end = rowptr[node + 1];
    for (int i = beg; i < end; ++i) {
        int s = csr_src[i];
        const float4 k4 = *(const float4*)&k[(size_t)s * D + lane * 4];
        float p = k4.x * q4.x + k4.y * q4.y + k4.z * q4.z + k4.w * q4.w;
        p += __shfl_xor(p, 1);
        p += __shfl_xor(p, 2);
        p += __shfl_xor(p, 4);
        float sc = __expf(fminf(fmaxf(p * inv_sqrt_dk, -5.f), 5.f));

        const float4 v4 = *(const float4*)&v[(size_t)s * D + lane * 4];
        acc.x += v4.x * sc;
        acc.y += v4.y * sc;
        acc.z += v4.z * sc;
        acc.w += v4.w * sc;
        zacc += sc;
    }
    float inv = 1.f / zacc;
    *(float4*)&o[(size_t)node * D + lane * 4] =
        make_float4(acc.x * inv, acc.y * inv, acc.z * inv, acc.w * inv);
}

// in-place LayerNorm over rows of length 256; one 256-thread block per row
__global__ __launch_bounds__(256) void layernorm_kernel(
    float* __restrict__ x, const float* __restrict__ g,
    const float* __restrict__ b, int M)
{
    int row = blockIdx.x;
    if (row >= M) return;
    int t = threadIdx.x;
    float val = x[(size_t)row * D + t];
    float s = val, s2 = val * val;
    #pragma unroll
    for (int o = 1; o < 64; o <<= 1) {
        s  += __shfl_xor(s, o);
        s2 += __shfl_xor(s2, o);
    }
    __shared__ float red[8];
    int wave = t >> 6;
    if ((t & 63) == 0) { red[wave] = s; red[4 + wave] = s2; }
    __syncthreads();
    s  = red[0] + red[1] + red[2] + red[3];
    s2 = red[4] + red[5] + red[6] + red[7];
    float mean = s * (1.f / 256.f);
    float var  = s2 * (1.f / 256.f) - mean * mean;
    float r = rsqrtf(var + 1e-5f);
    x[(size_t)row * D + t] = (val - mean) * r * g[t] + b[t];
}

// ---------------------------------------------------------------------------
extern "C" void kernel_launch(void* const* d_in, const int* in_sizes, int n_in,
                              void* d_out, int out_size, void* d_ws, size_t ws_size,
                              hipStream_t stream)
{
    const float* x0   = (const float*)d_in[0];
    const int* esrc   = (const int*)d_in[1];
    const int* edst   = (const int*)d_in[2];
    const float* Wq   = (const float*)d_in[3];
    const float* bq   = (const float*)d_in[4];
    const float* Wk   = (const float*)d_in[5];
    const float* Wv   = (const float*)d_in[6];
    const float* Wo   = (const float*)d_in[7];
    const float* bo   = (const float*)d_in[8];
    const float* ln1g = (const float*)d_in[9];
    const float* ln1b = (const float*)d_in[10];
    const float* W1   = (const float*)d_in[11];
    const float* b1   = (const float*)d_in[12];
    const float* W2   = (const float*)d_in[13];
    const float* b2   = (const float*)d_in[14];
    const float* ln2g = (const float*)d_in[15];
    const float* ln2b = (const float*)d_in[16];

    const int N = in_sizes[0] / D;
    const int E = in_sizes[1];
    const int L = in_sizes[3] / (D * D);
    const size_t ND = (size_t)N * D;

    // workspace (floats): bufX | q(=o) | k | v | ext ; then ints.
    //   t1 (N x DFF = 4*ND) aliases [q..ext] during FFN (all dead there)
    // total ~= 256 MB + 3.6 MB
    float* bufX = (float*)d_ws;
    float* q    = bufX + ND;
    float* k    = q + ND;
    float* v    = k + ND;
    float* ext  = v + ND;
    float* t1   = q;  // N x DFF spans q,k,v,ext

    int* rowptr  = (int*)(ext + ND);        // N+1
    int* cursor  = rowptr + (N + 1);        // N   (also used as deg)
    int* deg     = cursor;                  // alias (safe, see scan_write)
    int* csr_src = cursor + N;              // E
    int* bsum    = csr_src + E;             // <=256

    const int nb = cdiv(N, 256);

    dim3 blk(256);
    dim3 gQKV(cdiv(N, 64), D / 64);
    dim3 gFF1(cdiv(N, 64), DFF / 64);
    int edgeBlocks = cdiv(E, 256);
    int nodeBlocks = cdiv(N, 4);  // 4 waves (nodes) per block

    // ---- build CSR once per launch (graph identical across layers) ----
    zero_int_kernel<<<cdiv(N, 256), blk, 0, stream>>>(deg, N);
    count_deg_kernel<<<edgeBlocks, blk, 0, stream>>>(edst, deg, E);
    block_sum_kernel<<<nb, blk, 0, stream>>>(deg, bsum, N);
    scan_bsum_kernel<<<1, blk, 0, stream>>>(bsum, nb);
    scan_write_kernel<<<nb, blk, 0, stream>>>(deg, bsum, rowptr, cursor, N);
    fill_csr_kernel<<<edgeBlocks, blk, 0, stream>>>(esrc, edst, cursor, csr_src, E);

    const float* xin = x0;
    for (int l = 0; l < L; ++l) {
        float* xout = (l == L - 1) ? (float*)d_out : bufX;
        const float* Wq_l = Wq + (size_t)l * D * D;
        const float* Wk_l = Wk + (size_t)l * D * D;
        const float* Wv_l = Wv + (size_t)l * D * D;
        const float* Wo_l = Wo + (size_t)l * D * D;
        const float* W1_l = W1 + (size_t)l * D * DFF;
        const float* W2_l = W2 + (size_t)l * DFF * D;

        gemm_kernel<<<gQKV, blk, 0, stream>>>(xin, N, D, Wq_l, D, bq + l * D, nullptr, q, 0);
        gemm_kernel<<<gQKV, blk, 0, stream>>>(xin, N, D, Wk_l, D, nullptr, nullptr, k, 0);
        gemm_kernel<<<gQKV, blk, 0, stream>>>(xin, N, D, Wv_l, D, nullptr, nullptr, v, 0);

        // o (aliases q) = softmax-weighted aggregate, /z fused, no atomics
        node_attn_kernel<<<nodeBlocks, blk, 0, stream>>>(q, k, v, rowptr, csr_src, q, N);

        // h = LN(x + o@Wo + bo) -> xout
        gemm_kernel<<<gQKV, blk, 0, stream>>>(q, N, D, Wo_l, D, bo + l * D, xin, xout, 0);
        layernorm_kernel<<<N, blk, 0, stream>>>(xout, ln1g + l * D, ln1b + l * D, N);

        // ffn: t1 = relu(xout@W1 + b1); xout = LN(xout + t1@W2 + b2)
        gemm_kernel<<<gFF1, blk, 0, stream>>>(xout, N, D, W1_l, DFF, b1 + l * DFF, nullptr, t1, 1);
        gemm_kernel<<<gQKV, blk, 0, stream>>>(t1, N, DFF, W2_l, D, b2 + l * D, xout, xout, 0);
        layernorm_kernel<<<N, blk, 0, stream>>>(xout, ln2g + l * D, ln2b + l * D, N);

        xin = xout;
    }
}

// Round 4
// 4133.622 us; speedup vs baseline: 7.6128x; 2.6800x over previous
//
#include <hip/hip_runtime.h>
#include <cstdint>
#include <cstddef>

#define D 256
#define H 8
#define DFF 1024

typedef short s16x8 __attribute__((ext_vector_type(8)));
typedef float f32x4 __attribute__((ext_vector_type(4)));

static inline int cdiv(int a, int b) { return (a + b - 1) / b; }

__device__ inline uint16_t f2bf(float x) {
    unsigned u = __float_as_uint(x);
    u += 0x7FFFu + ((u >> 16) & 1u);
    return (uint16_t)(u >> 16);
}
__device__ inline float bf2f(uint16_t h) {
    return __uint_as_float(((unsigned)h) << 16);
}

__device__ inline void gload_lds16(const void* g, void* l) {
    __builtin_amdgcn_global_load_lds(
        (const __attribute__((address_space(1))) void*)g,
        (__attribute__((address_space(3))) void*)l, 16, 0, 0);
}

// ---------------------------------------------------------------------------
// CSR build (graph constant across layers)
// ---------------------------------------------------------------------------
__global__ __launch_bounds__(256) void zero_int_kernel(int* __restrict__ p, int count)
{
    int i = blockIdx.x * blockDim.x + threadIdx.x;
    if (i < count) p[i] = 0;
}

__global__ __launch_bounds__(256) void count_deg_kernel(
    const int* __restrict__ edst, int* __restrict__ deg, int E)
{
    int e = blockIdx.x * blockDim.x + threadIdx.x;
    if (e < E) atomicAdd(&deg[edst[e]], 1);
}

__global__ __launch_bounds__(256) void block_sum_kernel(
    const int* __restrict__ deg, int* __restrict__ bsum, int N)
{
    int t = threadIdx.x;
    int gid = blockIdx.x * 256 + t;
    int val = (gid < N) ? deg[gid] : 0;
    #pragma unroll
    for (int o = 1; o < 64; o <<= 1) val += __shfl_xor(val, o);
    __shared__ int r[4];
    if ((t & 63) == 0) r[t >> 6] = val;
    __syncthreads();
    if (t == 0) bsum[blockIdx.x] = r[0] + r[1] + r[2] + r[3];
}

__global__ __launch_bounds__(256) void scan_bsum_kernel(int* __restrict__ bsum, int nb)
{
    __shared__ int tmp[256];
    int t = threadIdx.x;
    int val = (t < nb) ? bsum[t] : 0;
    tmp[t] = val;
    __syncthreads();
    for (int off = 1; off < 256; off <<= 1) {
        int add = (t >= off) ? tmp[t - off] : 0;
        __syncthreads();
        tmp[t] += add;
        __syncthreads();
    }
    if (t < nb) bsum[t] = tmp[t] - val;
}

__global__ __launch_bounds__(256) void scan_write_kernel(
    const int* __restrict__ deg, const int* __restrict__ bsum,
    int* __restrict__ rowptr, int* __restrict__ cursor, int N)
{
    __shared__ int tmp[256];
    int t = threadIdx.x;
    int gid = blockIdx.x * 256 + t;
    int val = (gid < N) ? deg[gid] : 0;
    tmp[t] = val;
    __syncthreads();
    for (int off = 1; off < 256; off <<= 1) {
        int add = (t >= off) ? tmp[t - off] : 0;
        __syncthreads();
        tmp[t] += add;
        __syncthreads();
    }
    int excl = tmp[t] - val + bsum[blockIdx.x];
    if (gid < N) { rowptr[gid] = excl; cursor[gid] = excl; }
    if (gid == N - 1) rowptr[N] = excl + val;
}

__global__ __launch_bounds__(256) void fill_csr_kernel(
    const int* __restrict__ esrc, const int* __restrict__ edst,
    int* __restrict__ cursor, int* __restrict__ csr_src, int E)
{
    int e = blockIdx.x * blockDim.x + threadIdx.x;
    if (e < E) {
        int pos = atomicAdd(&cursor[edst[e]], 1);
        csr_src[pos] = esrc[e];
    }
}

// ---------------------------------------------------------------------------
// weight transpose+cast: out[c][r] = bf16(in[r][c]); per-z-slice matrices
// ---------------------------------------------------------------------------
__global__ __launch_bounds__(256) void transpose_cast_kernel(
    const float* __restrict__ in, uint16_t* __restrict__ out,
    int R, int C, size_t inLS, size_t outLS)
{
    __shared__ float t[32][33];
    in  += blockIdx.z * inLS;
    out += blockIdx.z * outLS;
    int c0 = blockIdx.x * 32, r0 = blockIdx.y * 32;
    int tx = threadIdx.x, ty = threadIdx.y;  // (32,8)
    #pragma unroll
    for (int i = 0; i < 4; ++i)
        t[ty + i * 8][tx] = in[(size_t)(r0 + ty + i * 8) * C + c0 + tx];
    __syncthreads();
    #pragma unroll
    for (int i = 0; i < 4; ++i)
        out[(size_t)(c0 + ty + i * 8) * R + r0 + tx] = f2bf(t[tx][ty + i * 8]);
}

__global__ __launch_bounds__(256) void cast_f32_bf16_kernel(
    const float* __restrict__ in, uint16_t* __restrict__ out, int n4)
{
    int i = blockIdx.x * blockDim.x + threadIdx.x;
    if (i >= n4) return;
    float4 f = ((const float4*)in)[i];
    uint16_t o0 = f2bf(f.x), o1 = f2bf(f.y), o2 = f2bf(f.z), o3 = f2bf(f.w);
    uint2 pk;
    pk.x = (unsigned)o0 | ((unsigned)o1 << 16);
    pk.y = (unsigned)o2 | ((unsigned)o3 << 16);
    ((uint2*)out)[i] = pk;
}

// qb[l][c] = (c<256) ? bq[l][c] : 0   over L*768
__global__ __launch_bounds__(256) void build_qkv_bias_kernel(
    const float* __restrict__ bq, float* __restrict__ qb, int total)
{
    int i = blockIdx.x * blockDim.x + threadIdx.x;
    if (i >= total) return;
    int l = i / 768, c = i - l * 768;
    qb[i] = (c < 256) ? bq[l * 256 + c] : 0.f;
}

// ---------------------------------------------------------------------------
// bf16 MFMA GEMM: C = A[M,K](lda) @ B (given as BT[Nc][K] bf16)
// 128x128 tile, 4 waves, 4x4 16x16x32 MFMA per wave, BK=32,
// global_load_lds width-16 staging (m97 recipe).
// Epilogue: +bias, +fp32 resid, relu, writes fp32 Cf and/or bf16 Cb.
// In-place safe for resid==Cf (same-thread read-then-write per element).
// ---------------------------------------------------------------------------
__global__ __launch_bounds__(256) void gemm_bf16_kernel(
    const uint16_t* __restrict__ A, int lda, int M, int K,
    const uint16_t* __restrict__ BT, int Nc,
    const float* __restrict__ bias,
    const float* __restrict__ resid,
    float* __restrict__ Cf, uint16_t* __restrict__ Cb, int relu)
{
    __shared__ __align__(16) uint16_t As[128 * 32];
    __shared__ __align__(16) uint16_t Bs[128 * 32];

    const int tid  = threadIdx.x;
    const int lane = tid & 63;
    const int w    = tid >> 6;
    const int wr   = w >> 1, wc = w & 1;
    const int quad = lane >> 4;
    const int l15  = lane & 15;

    const int m0 = blockIdx.x * 128;
    const int n0 = blockIdx.y * 128;

    f32x4 acc[4][4] = {};

    const int jbase = w * 2;
    const int srow  = lane >> 2;        // 0..15
    const int skc   = (lane & 3) * 8;   // k elem offset (16B chunks)

    for (int k0 = 0; k0 < K; k0 += 32) {
        #pragma unroll
        for (int jj = 0; jj < 2; ++jj) {
            int j = jbase + jj;
            int r = j * 16 + srow;
            int gr = m0 + r; if (gr > M - 1) gr = M - 1;   // clamp last tile
            gload_lds16(A  + (size_t)gr * lda + k0 + skc, &As[j * 512]);
            gload_lds16(BT + (size_t)(n0 + r) * K + k0 + skc, &Bs[j * 512]);
        }
        __syncthreads();

        s16x8 af[4], bf[4];
        #pragma unroll
        for (int t = 0; t < 4; ++t) {
            af[t] = *(const s16x8*)&As[(wr * 64 + t * 16 + l15) * 32 + quad * 8];
            bf[t] = *(const s16x8*)&Bs[(wc * 64 + t * 16 + l15) * 32 + quad * 8];
        }
        #pragma unroll
        for (int i = 0; i < 4; ++i)
            #pragma unroll
            for (int jt = 0; jt < 4; ++jt)
                acc[i][jt] = __builtin_amdgcn_mfma_f32_16x16x32_bf16(
                    af[i], bf[jt], acc[i][jt], 0, 0, 0);
        __syncthreads();
    }

    float bv[4];
    #pragma unroll
    for (int jt = 0; jt < 4; ++jt)
        bv[jt] = bias ? bias[n0 + wc * 64 + jt * 16 + l15] : 0.f;

    #pragma unroll
    for (int i = 0; i < 4; ++i) {
        #pragma unroll
        for (int r = 0; r < 4; ++r) {
            int m = m0 + wr * 64 + i * 16 + quad * 4 + r;
            if (m >= M) continue;
            #pragma unroll
            for (int jt = 0; jt < 4; ++jt) {
                int n = n0 + wc * 64 + jt * 16 + l15;
                float val = acc[i][jt][r] + bv[jt];
                if (resid) val += resid[(size_t)m * Nc + n];
                if (relu)  val = fmaxf(val, 0.f);
                if (Cf) Cf[(size_t)m * Nc + n] = val;
                if (Cb) Cb[(size_t)m * Nc + n] = f2bf(val);
            }
        }
    }
}

// ---------------------------------------------------------------------------
// Fused per-node attention: one wave per dst node; qkv bf16 [N][768] (q|k|v).
// fp32 accumulation; o written in-place over q slice (own-node only).
// ---------------------------------------------------------------------------
__global__ __launch_bounds__(256) void node_attn_kernel(
    uint16_t* __restrict__ qkv,
    const int* __restrict__ rowptr, const int* __restrict__ csr_src, int N)
{
    int node = (blockIdx.x * blockDim.x + threadIdx.x) >> 6;
    int lane = threadIdx.x & 63;
    if (node >= N) return;

    uint16_t* qp = qkv + (size_t)node * 768 + lane * 4;
    uint2 qu = *(const uint2*)qp;
    float q0 = bf2f((uint16_t)(qu.x & 0xFFFF)), q1 = bf2f((uint16_t)(qu.x >> 16));
    float q2 = bf2f((uint16_t)(qu.y & 0xFFFF)), q3 = bf2f((uint16_t)(qu.y >> 16));

    float a0 = 0.f, a1 = 0.f, a2 = 0.f, a3 = 0.f, zacc = 0.f;
    const float inv_sqrt_dk = 0.17677669529663687f;  // 1/sqrt(32)

    int beg = rowptr[node], end = rowptr[node + 1];
    for (int i = beg; i < end; ++i) {
        int s = csr_src[i];
        const uint16_t* base = qkv + (size_t)s * 768;
        uint2 ku = *(const uint2*)(base + 256 + lane * 4);
        float p = bf2f((uint16_t)(ku.x & 0xFFFF)) * q0
                + bf2f((uint16_t)(ku.x >> 16))   * q1
                + bf2f((uint16_t)(ku.y & 0xFFFF)) * q2
                + bf2f((uint16_t)(ku.y >> 16))   * q3;
        p += __shfl_xor(p, 1);
        p += __shfl_xor(p, 2);
        p += __shfl_xor(p, 4);
        float sc = __expf(fminf(fmaxf(p * inv_sqrt_dk, -5.f), 5.f));

        uint2 vu = *(const uint2*)(base + 512 + lane * 4);
        a0 += bf2f((uint16_t)(vu.x & 0xFFFF)) * sc;
        a1 += bf2f((uint16_t)(vu.x >> 16))   * sc;
        a2 += bf2f((uint16_t)(vu.y & 0xFFFF)) * sc;
        a3 += bf2f((uint16_t)(vu.y >> 16))   * sc;
        zacc += sc;
    }
    float inv = 1.f / zacc;
    uint2 pk;
    pk.x = (unsigned)f2bf(a0 * inv) | ((unsigned)f2bf(a1 * inv) << 16);
    pk.y = (unsigned)f2bf(a2 * inv) | ((unsigned)f2bf(a3 * inv) << 16);
    *(uint2*)qp = pk;
}

// ---------------------------------------------------------------------------
// in-place fp32 LayerNorm over rows of 256 + optional bf16 shadow copy
// ---------------------------------------------------------------------------
__global__ __launch_bounds__(256) void layernorm_kernel(
    float* __restrict__ x, const float* __restrict__ g,
    const float* __restrict__ b, uint16_t* __restrict__ xb, int M)
{
    int row = blockIdx.x;
    if (row >= M) return;
    int t = threadIdx.x;
    float val = x[(size_t)row * D + t];
    float s = val, s2 = val * val;
    #pragma unroll
    for (int o = 1; o < 64; o <<= 1) {
        s  += __shfl_xor(s, o);
        s2 += __shfl_xor(s2, o);
    }
    __shared__ float red[8];
    int wave = t >> 6;
    if ((t & 63) == 0) { red[wave] = s; red[4 + wave] = s2; }
    __syncthreads();
    s  = red[0] + red[1] + red[2] + red[3];
    s2 = red[4] + red[5] + red[6] + red[7];
    float mean = s * (1.f / 256.f);
    float var  = s2 * (1.f / 256.f) - mean * mean;
    float r = rsqrtf(var + 1e-5f);
    float out = (val - mean) * r * g[t] + b[t];
    x[(size_t)row * D + t] = out;
    if (xb) xb[(size_t)row * D + t] = f2bf(out);
}

// ---------------------------------------------------------------------------
extern "C" void kernel_launch(void* const* d_in, const int* in_sizes, int n_in,
                              void* d_out, int out_size, void* d_ws, size_t ws_size,
                              hipStream_t stream)
{
    const float* x0   = (const float*)d_in[0];
    const int* esrc   = (const int*)d_in[1];
    const int* edst   = (const int*)d_in[2];
    const float* Wq   = (const float*)d_in[3];
    const float* bq   = (const float*)d_in[4];
    const float* Wk   = (const float*)d_in[5];
    const float* Wv   = (const float*)d_in[6];
    const float* Wo   = (const float*)d_in[7];
    const float* bo   = (const float*)d_in[8];
    const float* ln1g = (const float*)d_in[9];
    const float* ln1b = (const float*)d_in[10];
    const float* W1   = (const float*)d_in[11];
    const float* b1   = (const float*)d_in[12];
    const float* W2   = (const float*)d_in[13];
    const float* b2   = (const float*)d_in[14];
    const float* ln2g = (const float*)d_in[15];
    const float* ln2b = (const float*)d_in[16];

    const int N = in_sizes[0] / D;
    const int E = in_sizes[1];
    const int L = in_sizes[3] / (D * D);
    const size_t ND = (size_t)N * D;

    // ---- workspace layout (~192 MB) ----
    char* p = (char*)d_ws;
    float* bufX = (float*)p;         p += ND * 4;            // fp32 residual stream
    uint16_t* xb  = (uint16_t*)p;                            // bf16 x (QKV input)
    uint16_t* t1  = xb;              p += ND * 2;            // t1 [N,1024] aliases xb+qkv
    uint16_t* qkv = (uint16_t*)p;    p += (size_t)N * 768 * 2;
    uint16_t* hb  = (uint16_t*)p;    p += ND * 2;            // bf16 h (FF1 input)
    uint16_t* BTqkv = (uint16_t*)p;  p += (size_t)L * 768 * 256 * 2;
    uint16_t* BTo   = (uint16_t*)p;  p += (size_t)L * 256 * 256 * 2;
    uint16_t* BT1   = (uint16_t*)p;  p += (size_t)L * 1024 * 256 * 2;
    uint16_t* BT2   = (uint16_t*)p;  p += (size_t)L * 256 * 1024 * 2;
    float* qbias    = (float*)p;     p += (size_t)L * 768 * 4;
    int* rowptr  = (int*)p;          p += (size_t)(N + 1) * 4;
    int* cursor  = (int*)p;          p += (size_t)N * 4;
    int* deg     = cursor;
    int* csr_src = (int*)p;          p += (size_t)E * 4;
    int* bsum    = (int*)p;

    const int nb = cdiv(N, 256);
    dim3 blk(256);
    int edgeBlocks = cdiv(E, 256);
    int nodeBlocks = cdiv(N, 4);

    // ---- one-time setup ----
    // weights -> bf16 transposed
    dim3 tb(32, 8);
    transpose_cast_kernel<<<dim3(8, 8, L), tb, 0, stream>>>(Wq, BTqkv, 256, 256, (size_t)65536, (size_t)768 * 256);
    transpose_cast_kernel<<<dim3(8, 8, L), tb, 0, stream>>>(Wk, BTqkv + 256 * 256, 256, 256, (size_t)65536, (size_t)768 * 256);
    transpose_cast_kernel<<<dim3(8, 8, L), tb, 0, stream>>>(Wv, BTqkv + 512 * 256, 256, 256, (size_t)65536, (size_t)768 * 256);
    transpose_cast_kernel<<<dim3(8, 8, L), tb, 0, stream>>>(Wo, BTo, 256, 256, (size_t)65536, (size_t)65536);
    transpose_cast_kernel<<<dim3(32, 8, L), tb, 0, stream>>>(W1, BT1, 256, 1024, (size_t)262144, (size_t)262144);
    transpose_cast_kernel<<<dim3(8, 32, L), tb, 0, stream>>>(W2, BT2, 1024, 256, (size_t)262144, (size_t)262144);
    build_qkv_bias_kernel<<<cdiv(L * 768, 256), blk, 0, stream>>>(bq, qbias, L * 768);
    cast_f32_bf16_kernel<<<cdiv((int)(ND / 4), 256), blk, 0, stream>>>(x0, xb, (int)(ND / 4));

    // CSR build
    zero_int_kernel<<<cdiv(N, 256), blk, 0, stream>>>(deg, N);
    count_deg_kernel<<<edgeBlocks, blk, 0, stream>>>(edst, deg, E);
    block_sum_kernel<<<nb, blk, 0, stream>>>(deg, bsum, N);
    scan_bsum_kernel<<<1, blk, 0, stream>>>(bsum, nb);
    scan_write_kernel<<<nb, blk, 0, stream>>>(deg, bsum, rowptr, cursor, N);
    fill_csr_kernel<<<edgeBlocks, blk, 0, stream>>>(esrc, edst, cursor, csr_src, E);

    const int Mt = cdiv(N, 128);
    dim3 gQKV(Mt, 768 / 128);
    dim3 gO(Mt, 256 / 128);
    dim3 gF1(Mt, 1024 / 128);
    dim3 gF2(Mt, 256 / 128);

    for (int l = 0; l < L; ++l) {
        const uint16_t* BTqkv_l = BTqkv + (size_t)l * 768 * 256;
        const uint16_t* BTo_l   = BTo + (size_t)l * 65536;
        const uint16_t* BT1_l   = BT1 + (size_t)l * 262144;
        const uint16_t* BT2_l   = BT2 + (size_t)l * 262144;
        const float* xin_f = (l == 0) ? x0 : bufX;

        // qkv = xb @ [Wq|Wk|Wv] + [bq|0|0]   (bf16 out, interleaved per node)
        gemm_bf16_kernel<<<gQKV, blk, 0, stream>>>(xb, 256, N, 256, BTqkv_l, 768,
            qbias + (size_t)l * 768, nullptr, nullptr, qkv, 0);

        // o (over q slice) = softmax-weighted aggregate
        node_attn_kernel<<<nodeBlocks, blk, 0, stream>>>(qkv, rowptr, csr_src, N);

        // bufX = xin + o@Wo + bo (fp32), then LN1 -> bufX fp32 + hb bf16
        gemm_bf16_kernel<<<gO, blk, 0, stream>>>(qkv, 768, N, 256, BTo_l, 256,
            bo + (size_t)l * 256, xin_f, bufX, nullptr, 0);
        layernorm_kernel<<<N, blk, 0, stream>>>(bufX, ln1g + l * 256, ln1b + l * 256, hb, N);

        // t1 = relu(h@W1 + b1) (bf16)
        gemm_bf16_kernel<<<gF1, blk, 0, stream>>>(hb, 256, N, 256, BT1_l, 1024,
            b1 + (size_t)l * 1024, nullptr, nullptr, t1, 1);

        // out = h + t1@W2 + b2 (fp32), then LN2 (+ bf16 xb for next layer)
        float* fout = (l == L - 1) ? (float*)d_out : bufX;
        gemm_bf16_kernel<<<gF2, blk, 0, stream>>>(t1, 1024, N, 1024, BT2_l, 256,
            b2 + (size_t)l * 256, bufX, fout, nullptr, 0);
        layernorm_kernel<<<N, blk, 0, stream>>>(fout, ln2g + l * 256, ln2b + l * 256,
            (l == L - 1) ? nullptr : xb, N);
    }
}

// Round 5
// 3422.681 us; speedup vs baseline: 9.1941x; 1.2077x over previous
//
#include <hip/hip_runtime.h>
#include <cstdint>
#include <cstddef>

#define D 256
#define H 8
#define DFF 1024

typedef short s16x8 __attribute__((ext_vector_type(8)));
typedef float f32x4 __attribute__((ext_vector_type(4)));

static inline int cdiv(int a, int b) { return (a + b - 1) / b; }

__device__ inline uint16_t f2bf(float x) {
    unsigned u = __float_as_uint(x);
    u += 0x7FFFu + ((u >> 16) & 1u);
    return (uint16_t)(u >> 16);
}
__device__ inline float bf2f(uint16_t h) {
    return __uint_as_float(((unsigned)h) << 16);
}

__device__ inline void gload_lds16(const void* g, void* l) {
    __builtin_amdgcn_global_load_lds(
        (const __attribute__((address_space(1))) void*)g,
        (__attribute__((address_space(3))) void*)l, 16, 0, 0);
}

// ---------------------------------------------------------------------------
// CSR build (graph constant across layers)
// ---------------------------------------------------------------------------
__global__ __launch_bounds__(256) void zero_int_kernel(int* __restrict__ p, int count)
{
    int i = blockIdx.x * blockDim.x + threadIdx.x;
    if (i < count) p[i] = 0;
}

__global__ __launch_bounds__(256) void count_deg_kernel(
    const int* __restrict__ edst, int* __restrict__ deg, int E)
{
    int e = blockIdx.x * blockDim.x + threadIdx.x;
    if (e < E) atomicAdd(&deg[edst[e]], 1);
}

__global__ __launch_bounds__(256) void block_sum_kernel(
    const int* __restrict__ deg, int* __restrict__ bsum, int N)
{
    int t = threadIdx.x;
    int gid = blockIdx.x * 256 + t;
    int val = (gid < N) ? deg[gid] : 0;
    #pragma unroll
    for (int o = 1; o < 64; o <<= 1) val += __shfl_xor(val, o);
    __shared__ int r[4];
    if ((t & 63) == 0) r[t >> 6] = val;
    __syncthreads();
    if (t == 0) bsum[blockIdx.x] = r[0] + r[1] + r[2] + r[3];
}

__global__ __launch_bounds__(256) void scan_bsum_kernel(int* __restrict__ bsum, int nb)
{
    __shared__ int tmp[256];
    int t = threadIdx.x;
    int val = (t < nb) ? bsum[t] : 0;
    tmp[t] = val;
    __syncthreads();
    for (int off = 1; off < 256; off <<= 1) {
        int add = (t >= off) ? tmp[t - off] : 0;
        __syncthreads();
        tmp[t] += add;
        __syncthreads();
    }
    if (t < nb) bsum[t] = tmp[t] - val;
}

__global__ __launch_bounds__(256) void scan_write_kernel(
    const int* __restrict__ deg, const int* __restrict__ bsum,
    int* __restrict__ rowptr, int* __restrict__ cursor, int N)
{
    __shared__ int tmp[256];
    int t = threadIdx.x;
    int gid = blockIdx.x * 256 + t;
    int val = (gid < N) ? deg[gid] : 0;
    tmp[t] = val;
    __syncthreads();
    for (int off = 1; off < 256; off <<= 1) {
        int add = (t >= off) ? tmp[t - off] : 0;
        __syncthreads();
        tmp[t] += add;
        __syncthreads();
    }
    int excl = tmp[t] - val + bsum[blockIdx.x];
    if (gid < N) { rowptr[gid] = excl; cursor[gid] = excl; }
    if (gid == N - 1) rowptr[N] = excl + val;
}

__global__ __launch_bounds__(256) void fill_csr_kernel(
    const int* __restrict__ esrc, const int* __restrict__ edst,
    int* __restrict__ cursor, int* __restrict__ csr_src, int E)
{
    int e = blockIdx.x * blockDim.x + threadIdx.x;
    if (e < E) {
        int pos = atomicAdd(&cursor[edst[e]], 1);
        csr_src[pos] = esrc[e];
    }
}

// ---------------------------------------------------------------------------
// weight transpose+cast: out[c][r] = bf16(in[r][c]); per-z-slice matrices
// ---------------------------------------------------------------------------
__global__ __launch_bounds__(256) void transpose_cast_kernel(
    const float* __restrict__ in, uint16_t* __restrict__ out,
    int R, int C, size_t inLS, size_t outLS)
{
    __shared__ float t[32][33];
    in  += blockIdx.z * inLS;
    out += blockIdx.z * outLS;
    int c0 = blockIdx.x * 32, r0 = blockIdx.y * 32;
    int tx = threadIdx.x, ty = threadIdx.y;  // (32,8)
    #pragma unroll
    for (int i = 0; i < 4; ++i)
        t[ty + i * 8][tx] = in[(size_t)(r0 + ty + i * 8) * C + c0 + tx];
    __syncthreads();
    #pragma unroll
    for (int i = 0; i < 4; ++i)
        out[(size_t)(c0 + ty + i * 8) * R + r0 + tx] = f2bf(t[tx][ty + i * 8]);
}

__global__ __launch_bounds__(256) void cast_f32_bf16_kernel(
    const float* __restrict__ in, uint16_t* __restrict__ out, int n4)
{
    int i = blockIdx.x * blockDim.x + threadIdx.x;
    if (i >= n4) return;
    float4 f = ((const float4*)in)[i];
    uint16_t o0 = f2bf(f.x), o1 = f2bf(f.y), o2 = f2bf(f.z), o3 = f2bf(f.w);
    uint2 pk;
    pk.x = (unsigned)o0 | ((unsigned)o1 << 16);
    pk.y = (unsigned)o2 | ((unsigned)o3 << 16);
    ((uint2*)out)[i] = pk;
}

__global__ __launch_bounds__(256) void build_qkv_bias_kernel(
    const float* __restrict__ bq, float* __restrict__ qb, int total)
{
    int i = blockIdx.x * blockDim.x + threadIdx.x;
    if (i >= total) return;
    int l = i / 768, c = i - l * 768;
    qb[i] = (c < 256) ? bq[l * 256 + c] : 0.f;
}

// ---------------------------------------------------------------------------
// bf16 MFMA GEMM (128x128 tile): used for QKV (Nc=768) and FF1 (Nc=1024).
// Epilogue: +bias, relu opt, writes bf16 Cb.
// ---------------------------------------------------------------------------
__global__ __launch_bounds__(256) void gemm_bf16_kernel(
    const uint16_t* __restrict__ A, int lda, int M, int K,
    const uint16_t* __restrict__ BT, int Nc,
    const float* __restrict__ bias,
    uint16_t* __restrict__ Cb, int relu)
{
    __shared__ __align__(16) uint16_t As[128 * 32];
    __shared__ __align__(16) uint16_t Bs[128 * 32];

    const int tid  = threadIdx.x;
    const int lane = tid & 63;
    const int w    = tid >> 6;
    const int wr   = w >> 1, wc = w & 1;
    const int quad = lane >> 4;
    const int l15  = lane & 15;

    const int m0 = blockIdx.x * 128;
    const int n0 = blockIdx.y * 128;

    f32x4 acc[4][4] = {};

    const int jbase = w * 2;
    const int srow  = lane >> 2;
    const int skc   = (lane & 3) * 8;

    for (int k0 = 0; k0 < K; k0 += 32) {
        #pragma unroll
        for (int jj = 0; jj < 2; ++jj) {
            int j = jbase + jj;
            int r = j * 16 + srow;
            int gr = m0 + r; if (gr > M - 1) gr = M - 1;
            gload_lds16(A  + (size_t)gr * lda + k0 + skc, &As[j * 512]);
            gload_lds16(BT + (size_t)(n0 + r) * K + k0 + skc, &Bs[j * 512]);
        }
        __syncthreads();

        s16x8 af[4], bf[4];
        #pragma unroll
        for (int t = 0; t < 4; ++t) {
            af[t] = *(const s16x8*)&As[(wr * 64 + t * 16 + l15) * 32 + quad * 8];
            bf[t] = *(const s16x8*)&Bs[(wc * 64 + t * 16 + l15) * 32 + quad * 8];
        }
        #pragma unroll
        for (int i = 0; i < 4; ++i)
            #pragma unroll
            for (int jt = 0; jt < 4; ++jt)
                acc[i][jt] = __builtin_amdgcn_mfma_f32_16x16x32_bf16(
                    af[i], bf[jt], acc[i][jt], 0, 0, 0);
        __syncthreads();
    }

    float bv[4];
    #pragma unroll
    for (int jt = 0; jt < 4; ++jt)
        bv[jt] = bias ? bias[n0 + wc * 64 + jt * 16 + l15] : 0.f;

    #pragma unroll
    for (int i = 0; i < 4; ++i) {
        #pragma unroll
        for (int r = 0; r < 4; ++r) {
            int m = m0 + wr * 64 + i * 16 + quad * 4 + r;
            if (m >= M) continue;
            #pragma unroll
            for (int jt = 0; jt < 4; ++jt) {
                int n = n0 + wc * 64 + jt * 16 + l15;
                float val = acc[i][jt][r] + bv[jt];
                if (relu) val = fmaxf(val, 0.f);
                Cb[(size_t)m * Nc + n] = f2bf(val);
            }
        }
    }
}

// ---------------------------------------------------------------------------
// bf16 MFMA GEMM + fused LayerNorm (Nc == 256 == one LN row per block-row).
// Tile 64Mx256N, 4 waves (each 64x64), BK=32, global_load_lds staging.
// epilogue: val = acc + bias + resid; row stats (shuffle + LDS across waves);
// out = LN(val)*g + b -> fp32 Cf (+ optional bf16 Cb shadow).
// In-place safe for resid==Cf (stats read before any write, block-local).
// ---------------------------------------------------------------------------
__global__ __launch_bounds__(256) void gemm_ln_kernel(
    const uint16_t* __restrict__ A, int lda, int M, int K,
    const uint16_t* __restrict__ BT,
    const float* __restrict__ bias,
    const float* __restrict__ resid,
    const float* __restrict__ g, const float* __restrict__ b,
    float* __restrict__ Cf, uint16_t* __restrict__ Cb)
{
    __shared__ __align__(16) uint16_t As[64 * 32];    //  4 KB
    __shared__ __align__(16) uint16_t Bs[256 * 32];   // 16 KB
    __shared__ float sS[64][4];                       //  1 KB
    __shared__ float sQ[64][4];                       //  1 KB

    const int tid  = threadIdx.x;
    const int lane = tid & 63;
    const int w    = tid >> 6;        // wave covers cols w*64..w*64+63
    const int quad = lane >> 4;
    const int l15  = lane & 15;

    const int m0 = blockIdx.x * 64;

    f32x4 acc[4][4] = {};

    for (int k0 = 0; k0 < K; k0 += 32) {
        // stage A (256 slots) + B (1024 slots), 16 B per slot, 5 slots/thread
        {
            int slot = tid;                       // A: slots 0..255
            int r = slot >> 2, kc = (slot & 3) * 8;
            int gr = m0 + r; if (gr > M - 1) gr = M - 1;
            gload_lds16(A + (size_t)gr * lda + k0 + kc, &As[slot * 8]);
        }
        #pragma unroll
        for (int i = 0; i < 4; ++i) {
            int slot = i * 256 + tid;             // B: slots 0..1023
            int n = slot >> 2, kc = (slot & 3) * 8;
            gload_lds16(BT + (size_t)n * K + k0 + kc, &Bs[slot * 8]);
        }
        __syncthreads();

        s16x8 af[4], bf[4];
        #pragma unroll
        for (int t = 0; t < 4; ++t) {
            af[t] = *(const s16x8*)&As[(t * 16 + l15) * 32 + quad * 8];
            bf[t] = *(const s16x8*)&Bs[(w * 64 + t * 16 + l15) * 32 + quad * 8];
        }
        #pragma unroll
        for (int i = 0; i < 4; ++i)
            #pragma unroll
            for (int jt = 0; jt < 4; ++jt)
                acc[i][jt] = __builtin_amdgcn_mfma_f32_16x16x32_bf16(
                    af[i], bf[jt], acc[i][jt], 0, 0, 0);
        __syncthreads();
    }

    float bv[4], gv[4], bbv[4];
    #pragma unroll
    for (int jt = 0; jt < 4; ++jt) {
        int n = w * 64 + jt * 16 + l15;
        bv[jt]  = bias[n];
        gv[jt]  = g[n];
        bbv[jt] = b[n];
    }

    // pass 1: val = acc + bias + resid (stored back into acc); row partial stats
    #pragma unroll
    for (int i = 0; i < 4; ++i) {
        #pragma unroll
        for (int r = 0; r < 4; ++r) {
            int ml = i * 16 + quad * 4 + r;       // local row 0..63
            int m  = m0 + ml;
            bool valid = (m < M);
            float s = 0.f, s2 = 0.f;
            #pragma unroll
            for (int jt = 0; jt < 4; ++jt) {
                int n = w * 64 + jt * 16 + l15;
                float val = acc[i][jt][r] + bv[jt];
                if (valid) val += resid[(size_t)m * 256 + n];
                acc[i][jt][r] = val;
                s += val;
                s2 += val * val;
            }
            #pragma unroll
            for (int o = 1; o < 16; o <<= 1) {
                s  += __shfl_xor(s, o);
                s2 += __shfl_xor(s2, o);
            }
            if (l15 == 0) { sS[ml][w] = s; sQ[ml][w] = s2; }
        }
    }
    __syncthreads();

    // pass 2: combine stats, normalize, write
    #pragma unroll
    for (int i = 0; i < 4; ++i) {
        #pragma unroll
        for (int r = 0; r < 4; ++r) {
            int ml = i * 16 + quad * 4 + r;
            int m  = m0 + ml;
            if (m >= M) continue;
            float s  = sS[ml][0] + sS[ml][1] + sS[ml][2] + sS[ml][3];
            float s2 = sQ[ml][0] + sQ[ml][1] + sQ[ml][2] + sQ[ml][3];
            float mean = s * (1.f / 256.f);
            float var  = s2 * (1.f / 256.f) - mean * mean;
            float rstd = rsqrtf(var + 1e-5f);
            #pragma unroll
            for (int jt = 0; jt < 4; ++jt) {
                int n = w * 64 + jt * 16 + l15;
                float out = (acc[i][jt][r] - mean) * rstd * gv[jt] + bbv[jt];
                Cf[(size_t)m * 256 + n] = out;
                if (Cb) Cb[(size_t)m * 256 + n] = f2bf(out);
            }
        }
    }
}

// ---------------------------------------------------------------------------
// Fused per-node attention: one wave per dst node; qkv bf16 [N][768] (q|k|v).
// ILP-2 edge unroll; fp32 accumulation; o in-place over q slice.
// ---------------------------------------------------------------------------
__global__ __launch_bounds__(256) void node_attn_kernel(
    uint16_t* __restrict__ qkv,
    const int* __restrict__ rowptr, const int* __restrict__ csr_src, int N)
{
    int node = (blockIdx.x * blockDim.x + threadIdx.x) >> 6;
    int lane = threadIdx.x & 63;
    if (node >= N) return;

    uint16_t* qp = qkv + (size_t)node * 768 + lane * 4;
    uint2 qu = *(const uint2*)qp;
    float q0 = bf2f((uint16_t)(qu.x & 0xFFFF)), q1 = bf2f((uint16_t)(qu.x >> 16));
    float q2 = bf2f((uint16_t)(qu.y & 0xFFFF)), q3 = bf2f((uint16_t)(qu.y >> 16));

    float a0 = 0.f, a1 = 0.f, a2 = 0.f, a3 = 0.f, zacc = 0.f;
    const float inv_sqrt_dk = 0.17677669529663687f;  // 1/sqrt(32)

    int beg = rowptr[node], end = rowptr[node + 1];
    int i = beg;
    for (; i + 1 < end; i += 2) {
        int s0 = csr_src[i], s1 = csr_src[i + 1];
        const uint16_t* b0 = qkv + (size_t)s0 * 768;
        const uint16_t* b1 = qkv + (size_t)s1 * 768;
        uint2 ku0 = *(const uint2*)(b0 + 256 + lane * 4);
        uint2 ku1 = *(const uint2*)(b1 + 256 + lane * 4);
        uint2 vu0 = *(const uint2*)(b0 + 512 + lane * 4);
        uint2 vu1 = *(const uint2*)(b1 + 512 + lane * 4);

        float p0 = bf2f((uint16_t)(ku0.x & 0xFFFF)) * q0
                 + bf2f((uint16_t)(ku0.x >> 16))   * q1
                 + bf2f((uint16_t)(ku0.y & 0xFFFF)) * q2
                 + bf2f((uint16_t)(ku0.y >> 16))   * q3;
        float p1 = bf2f((uint16_t)(ku1.x & 0xFFFF)) * q0
                 + bf2f((uint16_t)(ku1.x >> 16))   * q1
                 + bf2f((uint16_t)(ku1.y & 0xFFFF)) * q2
                 + bf2f((uint16_t)(ku1.y >> 16))   * q3;
        p0 += __shfl_xor(p0, 1); p1 += __shfl_xor(p1, 1);
        p0 += __shfl_xor(p0, 2); p1 += __shfl_xor(p1, 2);
        p0 += __shfl_xor(p0, 4); p1 += __shfl_xor(p1, 4);
        float sc0 = __expf(fminf(fmaxf(p0 * inv_sqrt_dk, -5.f), 5.f));
        float sc1 = __expf(fminf(fmaxf(p1 * inv_sqrt_dk, -5.f), 5.f));

        a0 += bf2f((uint16_t)(vu0.x & 0xFFFF)) * sc0;
        a1 += bf2f((uint16_t)(vu0.x >> 16))   * sc0;
        a2 += bf2f((uint16_t)(vu0.y & 0xFFFF)) * sc0;
        a3 += bf2f((uint16_t)(vu0.y >> 16))   * sc0;
        zacc += sc0;
        a0 += bf2f((uint16_t)(vu1.x & 0xFFFF)) * sc1;
        a1 += bf2f((uint16_t)(vu1.x >> 16))   * sc1;
        a2 += bf2f((uint16_t)(vu1.y & 0xFFFF)) * sc1;
        a3 += bf2f((uint16_t)(vu1.y >> 16))   * sc1;
        zacc += sc1;
    }
    if (i < end) {
        int s = csr_src[i];
        const uint16_t* base = qkv + (size_t)s * 768;
        uint2 ku = *(const uint2*)(base + 256 + lane * 4);
        float p = bf2f((uint16_t)(ku.x & 0xFFFF)) * q0
                + bf2f((uint16_t)(ku.x >> 16))   * q1
                + bf2f((uint16_t)(ku.y & 0xFFFF)) * q2
                + bf2f((uint16_t)(ku.y >> 16))   * q3;
        p += __shfl_xor(p, 1);
        p += __shfl_xor(p, 2);
        p += __shfl_xor(p, 4);
        float sc = __expf(fminf(fmaxf(p * inv_sqrt_dk, -5.f), 5.f));
        uint2 vu = *(const uint2*)(base + 512 + lane * 4);
        a0 += bf2f((uint16_t)(vu.x & 0xFFFF)) * sc;
        a1 += bf2f((uint16_t)(vu.x >> 16))   * sc;
        a2 += bf2f((uint16_t)(vu.y & 0xFFFF)) * sc;
        a3 += bf2f((uint16_t)(vu.y >> 16))   * sc;
        zacc += sc;
    }
    float inv = 1.f / zacc;
    uint2 pk;
    pk.x = (unsigned)f2bf(a0 * inv) | ((unsigned)f2bf(a1 * inv) << 16);
    pk.y = (unsigned)f2bf(a2 * inv) | ((unsigned)f2bf(a3 * inv) << 16);
    *(uint2*)qp = pk;
}

// ---------------------------------------------------------------------------
extern "C" void kernel_launch(void* const* d_in, const int* in_sizes, int n_in,
                              void* d_out, int out_size, void* d_ws, size_t ws_size,
                              hipStream_t stream)
{
    const float* x0   = (const float*)d_in[0];
    const int* esrc   = (const int*)d_in[1];
    const int* edst   = (const int*)d_in[2];
    const float* Wq   = (const float*)d_in[3];
    const float* bq   = (const float*)d_in[4];
    const float* Wk   = (const float*)d_in[5];
    const float* Wv   = (const float*)d_in[6];
    const float* Wo   = (const float*)d_in[7];
    const float* bo   = (const float*)d_in[8];
    const float* ln1g = (const float*)d_in[9];
    const float* ln1b = (const float*)d_in[10];
    const float* W1   = (const float*)d_in[11];
    const float* b1   = (const float*)d_in[12];
    const float* W2   = (const float*)d_in[13];
    const float* b2   = (const float*)d_in[14];
    const float* ln2g = (const float*)d_in[15];
    const float* ln2b = (const float*)d_in[16];

    const int N = in_sizes[0] / D;
    const int E = in_sizes[1];
    const int L = in_sizes[3] / (D * D);
    const size_t ND = (size_t)N * D;

    // ---- workspace layout ----
    char* p = (char*)d_ws;
    float* bufX = (float*)p;         p += ND * 4;            // fp32 residual stream
    uint16_t* xb  = (uint16_t*)p;                            // bf16 x (QKV input)
    uint16_t* t1  = xb;              p += ND * 2;            // t1 [N,1024] aliases xb+qkv
    uint16_t* qkv = (uint16_t*)p;    p += (size_t)N * 768 * 2;
    uint16_t* hb  = (uint16_t*)p;    p += ND * 2;            // bf16 h (FF1 input)
    uint16_t* BTqkv = (uint16_t*)p;  p += (size_t)L * 768 * 256 * 2;
    uint16_t* BTo   = (uint16_t*)p;  p += (size_t)L * 256 * 256 * 2;
    uint16_t* BT1   = (uint16_t*)p;  p += (size_t)L * 1024 * 256 * 2;
    uint16_t* BT2   = (uint16_t*)p;  p += (size_t)L * 256 * 1024 * 2;
    float* qbias    = (float*)p;     p += (size_t)L * 768 * 4;
    int* rowptr  = (int*)p;          p += (size_t)(N + 1) * 4;
    int* cursor  = (int*)p;          p += (size_t)N * 4;
    int* deg     = cursor;
    int* csr_src = (int*)p;          p += (size_t)E * 4;
    int* bsum    = (int*)p;

    const int nb = cdiv(N, 256);
    dim3 blk(256);
    int edgeBlocks = cdiv(E, 256);
    int nodeBlocks = cdiv(N, 4);

    // ---- one-time setup ----
    dim3 tb(32, 8);
    transpose_cast_kernel<<<dim3(8, 8, L), tb, 0, stream>>>(Wq, BTqkv, 256, 256, (size_t)65536, (size_t)768 * 256);
    transpose_cast_kernel<<<dim3(8, 8, L), tb, 0, stream>>>(Wk, BTqkv + 256 * 256, 256, 256, (size_t)65536, (size_t)768 * 256);
    transpose_cast_kernel<<<dim3(8, 8, L), tb, 0, stream>>>(Wv, BTqkv + 512 * 256, 256, 256, (size_t)65536, (size_t)768 * 256);
    transpose_cast_kernel<<<dim3(8, 8, L), tb, 0, stream>>>(Wo, BTo, 256, 256, (size_t)65536, (size_t)65536);
    transpose_cast_kernel<<<dim3(32, 8, L), tb, 0, stream>>>(W1, BT1, 256, 1024, (size_t)262144, (size_t)262144);
    transpose_cast_kernel<<<dim3(8, 32, L), tb, 0, stream>>>(W2, BT2, 1024, 256, (size_t)262144, (size_t)262144);
    build_qkv_bias_kernel<<<cdiv(L * 768, 256), blk, 0, stream>>>(bq, qbias, L * 768);
    cast_f32_bf16_kernel<<<cdiv((int)(ND / 4), 256), blk, 0, stream>>>(x0, xb, (int)(ND / 4));

    zero_int_kernel<<<cdiv(N, 256), blk, 0, stream>>>(deg, N);
    count_deg_kernel<<<edgeBlocks, blk, 0, stream>>>(edst, deg, E);
    block_sum_kernel<<<nb, blk, 0, stream>>>(deg, bsum, N);
    scan_bsum_kernel<<<1, blk, 0, stream>>>(bsum, nb);
    scan_write_kernel<<<nb, blk, 0, stream>>>(deg, bsum, rowptr, cursor, N);
    fill_csr_kernel<<<edgeBlocks, blk, 0, stream>>>(esrc, edst, cursor, csr_src, E);

    const int Mt128 = cdiv(N, 128);
    const int Mt64  = cdiv(N, 64);
    dim3 gQKV(Mt128, 768 / 128);
    dim3 gF1(Mt128, 1024 / 128);
    dim3 gLN(Mt64, 1);

    for (int l = 0; l < L; ++l) {
        const uint16_t* BTqkv_l = BTqkv + (size_t)l * 768 * 256;
        const uint16_t* BTo_l   = BTo + (size_t)l * 65536;
        const uint16_t* BT1_l   = BT1 + (size_t)l * 262144;
        const uint16_t* BT2_l   = BT2 + (size_t)l * 262144;
        const float* xin_f = (l == 0) ? x0 : bufX;

        // qkv = xb @ [Wq|Wk|Wv] + [bq|0|0]   (bf16, interleaved per node)
        gemm_bf16_kernel<<<gQKV, blk, 0, stream>>>(xb, 256, N, 256, BTqkv_l, 768,
            qbias + (size_t)l * 768, qkv, 0);

        // o (over q slice) = softmax-weighted aggregate
        node_attn_kernel<<<nodeBlocks, blk, 0, stream>>>(qkv, rowptr, csr_src, N);

        // bufX = LN1(xin + o@Wo + bo)  (fused)  -> fp32 bufX + bf16 hb
        gemm_ln_kernel<<<gLN, blk, 0, stream>>>(qkv, 768, N, 256, BTo_l,
            bo + (size_t)l * 256, xin_f, ln1g + (size_t)l * 256, ln1b + (size_t)l * 256,
            bufX, hb);

        // t1 = relu(h@W1 + b1) (bf16)
        gemm_bf16_kernel<<<gF1, blk, 0, stream>>>(hb, 256, N, 256, BT1_l, 1024,
            b1 + (size_t)l * 1024, t1, 1);

        // fout = LN2(h + t1@W2 + b2)  (fused)  -> fp32 fout + bf16 xb
        float* fout = (l == L - 1) ? (float*)d_out : bufX;
        gemm_ln_kernel<<<gLN, blk, 0, stream>>>(t1, 1024, N, 1024, BT2_l,
            b2 + (size_t)l * 256, bufX, ln2g + (size_t)l * 256, ln2b + (size_t)l * 256,
            fout, (l == L - 1) ? nullptr : xb);

        xin_f = bufX;
    }
}